// Round 5
// baseline (100.695 us; speedup 1.0000x reference)
//
#include <hip/hip_runtime.h>
#include <hip/hip_bf16.h>

// StatDynamicConv2d: routing MLP -> expert-mixed 3x3 conv (per-sample weights)
// B=32, Cin=Cout=128, H=W=64, E=4, K=3, pad=1, stride=1.
//
// ws layout (~45.2 MB):
//   [0,512)                routing[32][4] f32
//   [512, 512+16384)       dynb[32][128] f32
//   [32768, +9437184)      dynw[32][4cic][9tap][8mi][64lane][8] bf16
//                          (MFMA A-fragment order: lane=g*16+l15 holds
//                           co=16*mi+l15, ci=g*8+j of the 32-ci chunk)
//   [9469952, +35684352)   xbfT[32][4cic][66][66][32ci] bf16, halo baked,
//                          16B chunk cg stored at (cg + (lcol>>1))&3

typedef short bf16x8 __attribute__((ext_vector_type(8)));
typedef float f32x4  __attribute__((ext_vector_type(4)));

static __device__ __forceinline__ unsigned short f2bf(float f) {
    unsigned u = __float_as_uint(f);
    u = u + 0x7FFFu + ((u >> 16) & 1u);   // round-to-nearest-even
    return (unsigned short)(u >> 16);
}

static __device__ __forceinline__ void gl2lds16(const unsigned short* g, unsigned short* l) {
    __builtin_amdgcn_global_load_lds(
        (const __attribute__((address_space(1))) unsigned int*)g,
        (__attribute__((address_space(3))) unsigned int*)l,
        16, 0, 0);
}

// ---------------- kernel A: router MLP ----------------
__global__ void router_kernel(const float* __restrict__ stats, const float* __restrict__ W1,
                              const float* __restrict__ b1, const float* __restrict__ W2,
                              const float* __restrict__ b2, float* __restrict__ routing)
{
    int t = threadIdx.x;
    if (t >= 32) return;
    float s[6];
#pragma unroll
    for (int i = 0; i < 6; ++i) s[i] = stats[t*6 + i];
    float h[16];
#pragma unroll
    for (int j = 0; j < 16; ++j) {
        float a = b1[j];
#pragma unroll
        for (int i = 0; i < 6; ++i) a += W1[j*6+i]*s[i];
        h[j] = a > 0.f ? a : 0.f;
    }
    float lg[4];
#pragma unroll
    for (int e = 0; e < 4; ++e) {
        float a = b2[e];
#pragma unroll
        for (int j = 0; j < 16; ++j) a += W2[e*16+j]*h[j];
        lg[e] = a;
    }
    float m = fmaxf(fmaxf(lg[0],lg[1]), fmaxf(lg[2],lg[3]));
    float ex[4], sum = 0.f;
#pragma unroll
    for (int e = 0; e < 4; ++e) { ex[e] = expf(lg[e]-m); sum += ex[e]; }
    float inv = 1.f / sum;
#pragma unroll
    for (int e = 0; e < 4; ++e) routing[t*4+e] = ex[e]*inv;
}

// ---------------- kernel B: dynamic weights (bf16, fragment-ordered) + dyn bias ----------------
__global__ void dynw_kernel(const float* __restrict__ wexp, const float* __restrict__ bexp,
                            const float* __restrict__ routing, unsigned short* __restrict__ dynw,
                            float* __restrict__ dynb)
{
    __shared__ float ls[4*1152];
    __shared__ float lr[32*4];
    const int tid = threadIdx.x;
    const int co  = blockIdx.x;
    const int bg  = blockIdx.y;

    for (int i = tid; i < 4*1152; i += 256) {
        int e = i / 1152, j = i - e*1152;
        ls[i] = wexp[((unsigned long long)(e*128 + co))*1152 + j];
    }
    if (tid < 128) lr[tid] = routing[tid];
    __syncthreads();

    if (bg == 0 && tid < 32) {
        float sb = 0.f;
#pragma unroll
        for (int e = 0; e < 4; ++e) sb += lr[tid*4+e] * bexp[e*128 + co];
        dynb[tid*128 + co] = sb;
    }

    const int ci  = tid & 127;
    const int tp0 = tid >> 7;
    const int cic = ci >> 5;
    const int g   = (ci >> 3) & 3;
    const int jj  = ci & 7;
    const int mi  = co >> 4;
    const int l15 = co & 15;
    for (int bb = bg*8; bb < bg*8 + 8; ++bb) {
        float r0 = lr[bb*4+0], r1 = lr[bb*4+1], r2 = lr[bb*4+2], r3 = lr[bb*4+3];
#pragma unroll
        for (int pp = 0; pp < 5; ++pp) {
            int tap = 2*pp + tp0;
            if (tap < 9) {
                int j = ci*9 + tap;
                float v = r0*ls[j] + r1*ls[1152+j] + r2*ls[2*1152+j] + r3*ls[3*1152+j];
                dynw[((((unsigned long long)(bb*4 + cic)*9 + tap)*8 + mi)*64 + g*16 + l15)*8 + jj] = f2bf(v);
            }
        }
    }
}

// ---------------- kernel C: x fp32 -> bf16, transposed + halo + swizzle baked ----------------
// grid 32*66 blocks, 256 threads
__global__ void xcvt_kernel(const float* __restrict__ x, unsigned short* __restrict__ xbfT)
{
    __shared__ unsigned int ls32[64*66];
    const int tid = threadIdx.x;
    const int b  = blockIdx.x / 66;
    const int rr = blockIdx.x - b*66;
    const int gr = rr - 1;

    if (gr < 0 || gr > 63) {
        for (int cic = 0; cic < 4; ++cic) {
            int4* dst = (int4*)(xbfT + ((unsigned long long)((b*4 + cic)*66 + rr))*(66*32));
            for (int d = tid; d < 264; d += 256) dst[d] = make_int4(0,0,0,0);
        }
        return;
    }
    const int lane = tid & 63;
    const int w    = tid >> 6;
#pragma unroll
    for (int k = 0; k < 16; ++k) {
        int cp = w + 4*k;   // ci pair 0..63
        const float* p0 = x + (((unsigned long long)b*128 + 2*cp)*64 + gr)*64 + lane;
        unsigned lo = f2bf(p0[0]);
        unsigned hi = f2bf(p0[64*64]);
        ls32[cp*66 + lane] = lo | (hi << 16);
    }
    __syncthreads();
    for (int d = tid; d < 1056; d += 256) {
        int cic  = d / 264;
        int r    = d - cic*264;
        int lcol = r >> 2;
        int cg   = r & 3;
        int4 v;
        if (lcol == 0 || lcol == 65) {
            v = make_int4(0,0,0,0);
        } else {
            int col  = lcol - 1;
            int base = (cic*16 + cg*4)*66 + col;
            v.x = ls32[base];
            v.y = ls32[base + 66];
            v.z = ls32[base + 2*66];
            v.w = ls32[base + 3*66];
        }
        int p = (cg + (lcol >> 1)) & 3;             // bank-conflict-free swizzle
        int4* dst = (int4*)(xbfT + ((unsigned long long)((b*4 + cic)*66 + rr))*(66*32));
        dst[lcol*4 + p] = v;
    }
}

// ---------------- kernel D: implicit-GEMM conv, bf16 MFMA ----------------
// grid 512 (32 b x 16 4-row tiles), 256 threads (4 waves).
// Wave = (cout-half, row-pair): ch = wave&1 (64 co), rp = wave>>1 (2 rows).
// Weights global->VGPR with explicit rotating double-buffer (prefetch dist 1).
__global__ __launch_bounds__(256, 2) void conv_kernel(
    const unsigned short* __restrict__ xbfT,
    const unsigned short* __restrict__ dynw,
    const float* __restrict__ dynb,
    float* __restrict__ out)
{
    __shared__ __align__(16) unsigned short xs[2][6*66*32];   // 2 x 25344 B

    const int tid  = threadIdx.x;
    const int wave = tid >> 6;
    const int lane = tid & 63;
    const int l15  = lane & 15;
    const int g    = lane >> 4;
    const int ch   = wave & 1;       // cout half (0..1)
    const int rp   = wave >> 1;      // row pair  (0..1): rows r0+2*rp+{0,1}

    // bijective XCD swizzle (512 blocks, 8 XCDs -> 64 contiguous per XCD)
    int bidx = ((blockIdx.x & 7) << 6) | (blockIdx.x >> 3);
    const int b  = bidx >> 4;
    const int r0 = (bidx & 15) << 2;

    f32x4 acc[4][8];
#pragma unroll
    for (int mi = 0; mi < 4; ++mi)
#pragma unroll
        for (int ni = 0; ni < 8; ++ni) acc[mi][ni] = (f32x4){0.f,0.f,0.f,0.f};

    const unsigned short* xsrcb = xbfT + (unsigned long long)b*(4ull*66*66*32);
    // per-wave weight base: this wave's cout-half fragments, own lane's 16B
    const unsigned short* wsrcb = dynw + (unsigned long long)b*(4ull*9*4096)
                                + (unsigned)ch*2048 + (unsigned)lane*8;

    bf16x8 wbuf[2][4];

    // prologue: prefetch step-0 weights FIRST (oldest in vmcnt queue), then stage xs[0]
#pragma unroll
    for (int mi = 0; mi < 4; ++mi)
        wbuf[0][mi] = *(const bf16x8*)(wsrcb + mi*512);
    {
        const unsigned short* src = xsrcb + (unsigned)r0*(66*32);
        for (int c = tid; c < 1584; c += 256) gl2lds16(src + c*8, xs[0] + c*8);
    }
    __syncthreads();

#pragma unroll
    for (int cic = 0; cic < 4; ++cic) {
        const unsigned short* xb = xs[cic & 1];
#pragma unroll
        for (int tap = 0; tap < 9; ++tap) {
            const int s   = cic*9 + tap;       // static after unroll
            const int cur = s & 1, nxt = cur ^ 1;
            // prefetch next step's weights into the other buffer (covered by this
            // step's 32 MFMAs; WAR on wbuf pins prefetch distance = 1)
            const int sn = (s < 35) ? s + 1 : 35;
#pragma unroll
            for (int mi = 0; mi < 4; ++mi)
                wbuf[nxt][mi] = *(const bf16x8*)(wsrcb + (unsigned)(sn*4096 + mi*512));
            if (tap == 0 && cic < 3) {   // stage next ci-chunk (drained at cic-end barrier)
                const unsigned short* src = xsrcb + (unsigned)(cic+1)*(66*66*32)
                                          + (unsigned)r0*(66*32);
                unsigned short* dstl = xs[(cic & 1) ^ 1];
                for (int c = tid; c < 1584; c += 256) gl2lds16(src + c*8, dstl + c*8);
            }
            const int ky = tap / 3, kx = tap - ky*3;
            bf16x8 bfrag[8];
#pragma unroll
            for (int ni = 0; ni < 8; ++ni) {
                int lrow = 2*rp + (ni >> 2) + ky;
                int lcol = 16*(ni & 3) + l15 + kx;
                int boff = (lrow*66 + lcol)*64 + (((g + (lcol >> 1)) & 3) << 4);
                bfrag[ni] = *(const bf16x8*)((const char*)xb + boff);
            }
#pragma unroll
            for (int mi = 0; mi < 4; ++mi) {
#pragma unroll
                for (int ni = 0; ni < 8; ++ni)
                    acc[mi][ni] = __builtin_amdgcn_mfma_f32_16x16x32_bf16(
                                      wbuf[cur][mi], bfrag[ni], acc[mi][ni], 0, 0, 0);
            }
        }
        __syncthreads();   // one barrier per ci-chunk
    }

    // epilogue: co = ch*64 + 16*mi + g*4 + r ; y = r0 + 2*rp + (ni>>2) ; x = 16*(ni&3)+l15
#pragma unroll
    for (int mi = 0; mi < 4; ++mi) {
#pragma unroll
        for (int r = 0; r < 4; ++r) {
            int co = ch*64 + 16*mi + g*4 + r;
            float bias = dynb[b*128 + co];
            const float* accbase;
#pragma unroll
            for (int ni = 0; ni < 8; ++ni) {
                int y = r0 + 2*rp + (ni >> 2);
                float* op = out + (((unsigned long long)(b*128 + co))*64 + y)*64;
                op[16*(ni & 3) + l15] = acc[mi][ni][r] + bias;
            }
        }
    }
}

extern "C" void kernel_launch(void* const* d_in, const int* in_sizes, int n_in,
                              void* d_out, int out_size, void* d_ws, size_t ws_size,
                              hipStream_t stream)
{
    const float* x     = (const float*)d_in[0];
    const float* stats = (const float*)d_in[1];
    const float* W1    = (const float*)d_in[2];
    const float* b1    = (const float*)d_in[3];
    const float* W2    = (const float*)d_in[4];
    const float* b2    = (const float*)d_in[5];
    const float* wexp  = (const float*)d_in[6];
    const float* bexp  = (const float*)d_in[7];
    float* out = (float*)d_out;

    char* ws = (char*)d_ws;
    float* routing        = (float*)ws;                              // 512 B
    float* dynb           = (float*)(ws + 512);                      // 16 KB
    unsigned short* dynw  = (unsigned short*)(ws + 32768);           // 9,437,184 B
    unsigned short* xbfT  = (unsigned short*)(ws + 32768 + 9437184); // 35,684,352 B

    router_kernel<<<1, 64, 0, stream>>>(stats, W1, b1, W2, b2, routing);
    dynw_kernel<<<dim3(128, 4), 256, 0, stream>>>(wexp, bexp, routing, dynw, dynb);
    xcvt_kernel<<<32*66, 256, 0, stream>>>(x, xbfT);
    conv_kernel<<<512, 256, 0, stream>>>(xbfT, dynw, dynb, out);
}

// Round 6
// 96.306 us; speedup vs baseline: 1.0456x; 1.0456x over previous
//
#include <hip/hip_runtime.h>
#include <hip/hip_bf16.h>

// StatDynamicConv2d: routing MLP -> expert-mixed 3x3 conv (per-sample weights)
// B=32, Cin=Cout=128, H=W=64, E=4, K=3, pad=1, stride=1.
//
// ws layout (~45.2 MB):
//   [0,512)                routing[32][4] f32
//   [512, 512+16384)       dynb[32][128] f32
//   [32768, +9437184)      dynw[32][4cic][9tap][8mi][64lane][8] bf16
//                          (MFMA A-fragment order: lane=g*16+l15 holds
//                           co=16*mi+l15, ci=g*8+j of the 32-ci chunk)
//   [9469952, +35684352)   xbfT[32][4cic][66][66][32ci] bf16, halo baked,
//                          16B chunk cg stored at (cg + (lcol>>1))&3

typedef short bf16x8 __attribute__((ext_vector_type(8)));
typedef float f32x4  __attribute__((ext_vector_type(4)));

static __device__ __forceinline__ unsigned short f2bf(float f) {
    unsigned u = __float_as_uint(f);
    u = u + 0x7FFFu + ((u >> 16) & 1u);   // round-to-nearest-even
    return (unsigned short)(u >> 16);
}

static __device__ __forceinline__ void gl2lds16(const unsigned short* g, unsigned short* l) {
    __builtin_amdgcn_global_load_lds(
        (const __attribute__((address_space(1))) unsigned int*)g,
        (__attribute__((address_space(3))) unsigned int*)l,
        16, 0, 0);
}

// ---------------- kernel A: router MLP ----------------
__global__ void router_kernel(const float* __restrict__ stats, const float* __restrict__ W1,
                              const float* __restrict__ b1, const float* __restrict__ W2,
                              const float* __restrict__ b2, float* __restrict__ routing)
{
    int t = threadIdx.x;
    if (t >= 32) return;
    float s[6];
#pragma unroll
    for (int i = 0; i < 6; ++i) s[i] = stats[t*6 + i];
    float h[16];
#pragma unroll
    for (int j = 0; j < 16; ++j) {
        float a = b1[j];
#pragma unroll
        for (int i = 0; i < 6; ++i) a += W1[j*6+i]*s[i];
        h[j] = a > 0.f ? a : 0.f;
    }
    float lg[4];
#pragma unroll
    for (int e = 0; e < 4; ++e) {
        float a = b2[e];
#pragma unroll
        for (int j = 0; j < 16; ++j) a += W2[e*16+j]*h[j];
        lg[e] = a;
    }
    float m = fmaxf(fmaxf(lg[0],lg[1]), fmaxf(lg[2],lg[3]));
    float ex[4], sum = 0.f;
#pragma unroll
    for (int e = 0; e < 4; ++e) { ex[e] = expf(lg[e]-m); sum += ex[e]; }
    float inv = 1.f / sum;
#pragma unroll
    for (int e = 0; e < 4; ++e) routing[t*4+e] = ex[e]*inv;
}

// ---------------- kernel B: dynamic weights (bf16, fragment-ordered) + dyn bias ----------------
__global__ void dynw_kernel(const float* __restrict__ wexp, const float* __restrict__ bexp,
                            const float* __restrict__ routing, unsigned short* __restrict__ dynw,
                            float* __restrict__ dynb)
{
    __shared__ float ls[4*1152];
    __shared__ float lr[32*4];
    const int tid = threadIdx.x;
    const int co  = blockIdx.x;
    const int bg  = blockIdx.y;

    for (int i = tid; i < 4*1152; i += 256) {
        int e = i / 1152, j = i - e*1152;
        ls[i] = wexp[((unsigned long long)(e*128 + co))*1152 + j];
    }
    if (tid < 128) lr[tid] = routing[tid];
    __syncthreads();

    if (bg == 0 && tid < 32) {
        float sb = 0.f;
#pragma unroll
        for (int e = 0; e < 4; ++e) sb += lr[tid*4+e] * bexp[e*128 + co];
        dynb[tid*128 + co] = sb;
    }

    const int ci  = tid & 127;
    const int tp0 = tid >> 7;
    const int cic = ci >> 5;
    const int g   = (ci >> 3) & 3;
    const int jj  = ci & 7;
    const int mi  = co >> 4;
    const int l15 = co & 15;
    for (int bb = bg*8; bb < bg*8 + 8; ++bb) {
        float r0 = lr[bb*4+0], r1 = lr[bb*4+1], r2 = lr[bb*4+2], r3 = lr[bb*4+3];
#pragma unroll
        for (int pp = 0; pp < 5; ++pp) {
            int tap = 2*pp + tp0;
            if (tap < 9) {
                int j = ci*9 + tap;
                float v = r0*ls[j] + r1*ls[1152+j] + r2*ls[2*1152+j] + r3*ls[3*1152+j];
                dynw[((((unsigned long long)(bb*4 + cic)*9 + tap)*8 + mi)*64 + g*16 + l15)*8 + jj] = f2bf(v);
            }
        }
    }
}

// ---------------- kernel C: x fp32 -> bf16, transposed + halo + swizzle baked ----------------
// grid 32*66 blocks, 256 threads
__global__ void xcvt_kernel(const float* __restrict__ x, unsigned short* __restrict__ xbfT)
{
    __shared__ unsigned int ls32[64*66];
    const int tid = threadIdx.x;
    const int b  = blockIdx.x / 66;
    const int rr = blockIdx.x - b*66;
    const int gr = rr - 1;

    if (gr < 0 || gr > 63) {
        for (int cic = 0; cic < 4; ++cic) {
            int4* dst = (int4*)(xbfT + ((unsigned long long)((b*4 + cic)*66 + rr))*(66*32));
            for (int d = tid; d < 264; d += 256) dst[d] = make_int4(0,0,0,0);
        }
        return;
    }
    const int lane = tid & 63;
    const int w    = tid >> 6;
#pragma unroll
    for (int k = 0; k < 16; ++k) {
        int cp = w + 4*k;   // ci pair 0..63
        const float* p0 = x + (((unsigned long long)b*128 + 2*cp)*64 + gr)*64 + lane;
        unsigned lo = f2bf(p0[0]);
        unsigned hi = f2bf(p0[64*64]);
        ls32[cp*66 + lane] = lo | (hi << 16);
    }
    __syncthreads();
    for (int d = tid; d < 1056; d += 256) {
        int cic  = d / 264;
        int r    = d - cic*264;
        int lcol = r >> 2;
        int cg   = r & 3;
        int4 v;
        if (lcol == 0 || lcol == 65) {
            v = make_int4(0,0,0,0);
        } else {
            int col  = lcol - 1;
            int base = (cic*16 + cg*4)*66 + col;
            v.x = ls32[base];
            v.y = ls32[base + 66];
            v.z = ls32[base + 2*66];
            v.w = ls32[base + 3*66];
        }
        int p = (cg + (lcol >> 1)) & 3;             // bank-conflict-free swizzle
        int4* dst = (int4*)(xbfT + ((unsigned long long)((b*4 + cic)*66 + rr))*(66*32));
        dst[lcol*4 + p] = v;
    }
}

// ---------------- kernel D: implicit-GEMM conv, bf16 MFMA ----------------
// grid 512 (32 b x 16 4-row tiles), 512 threads (8 waves).
// Wave = (ch = wave&1: cout half, row = wave>>1: output row 0..3).
// acc = 4mi x 4ni = 64 VGPRs/thread; weights global->VGPR, rotating
// double-buffer prefetch distance 1; 2 blocks/CU -> 4 waves/SIMD.
__global__ __launch_bounds__(512, 4) void conv_kernel(
    const unsigned short* __restrict__ xbfT,
    const unsigned short* __restrict__ dynw,
    const float* __restrict__ dynb,
    float* __restrict__ out)
{
    __shared__ __align__(16) unsigned short xs[2][6*66*32];   // 2 x 25344 B

    const int tid  = threadIdx.x;
    const int wave = tid >> 6;
    const int lane = tid & 63;
    const int l15  = lane & 15;
    const int g    = lane >> 4;
    const int ch   = wave & 1;       // cout half (0..1)
    const int row  = wave >> 1;      // output row within tile (0..3)

    // bijective XCD swizzle (512 blocks, 8 XCDs -> 64 contiguous per XCD)
    int bidx = ((blockIdx.x & 7) << 6) | (blockIdx.x >> 3);
    const int b  = bidx >> 4;
    const int r0 = (bidx & 15) << 2;

    f32x4 acc[4][4];
#pragma unroll
    for (int mi = 0; mi < 4; ++mi)
#pragma unroll
        for (int ni = 0; ni < 4; ++ni) acc[mi][ni] = (f32x4){0.f,0.f,0.f,0.f};

    const unsigned short* xsrcb = xbfT + (unsigned long long)b*(4ull*66*66*32);
    // per-wave weight base: this wave's cout-half fragments, own lane's 16B
    const unsigned short* wsrcb = dynw + (unsigned long long)b*(4ull*9*4096)
                                + (unsigned)ch*2048 + (unsigned)lane*8;

    bf16x8 wbuf[2][4];

    // prologue: prefetch step-0 weights, then stage xs[0]
#pragma unroll
    for (int mi = 0; mi < 4; ++mi)
        wbuf[0][mi] = *(const bf16x8*)(wsrcb + mi*512);
    {
        const unsigned short* src = xsrcb + (unsigned)r0*(66*32);
        for (int c = tid; c < 1584; c += 512) gl2lds16(src + c*8, xs[0] + c*8);
    }
    __syncthreads();

#pragma unroll
    for (int cic = 0; cic < 4; ++cic) {
        const unsigned short* xb = xs[cic & 1];
#pragma unroll
        for (int tap = 0; tap < 9; ++tap) {
            const int s   = cic*9 + tap;       // static after unroll
            const int cur = s & 1, nxt = cur ^ 1;
            // prefetch next step's weights (covered by this step's 16 MFMAs;
            // WAR on wbuf pins prefetch distance = 1)
            const int sn = (s < 35) ? s + 1 : 35;
#pragma unroll
            for (int mi = 0; mi < 4; ++mi)
                wbuf[nxt][mi] = *(const bf16x8*)(wsrcb + (unsigned)(sn*4096 + mi*512));
            if (tap == 0 && cic < 3) {   // stage next ci-chunk (drained at cic-end barrier)
                const unsigned short* src = xsrcb + (unsigned)(cic+1)*(66*66*32)
                                          + (unsigned)r0*(66*32);
                unsigned short* dstl = xs[(cic & 1) ^ 1];
                for (int c = tid; c < 1584; c += 512) gl2lds16(src + c*8, dstl + c*8);
            }
            const int ky = tap / 3, kx = tap - ky*3;
            const int lrow = row + ky;
#pragma unroll
            for (int ni = 0; ni < 4; ++ni) {
                int lcol = 16*ni + l15 + kx;
                int boff = (lrow*66 + lcol)*64 + (((g + (lcol >> 1)) & 3) << 4);
                bf16x8 bfrag = *(const bf16x8*)((const char*)xb + boff);
#pragma unroll
                for (int mi = 0; mi < 4; ++mi)
                    acc[mi][ni] = __builtin_amdgcn_mfma_f32_16x16x32_bf16(
                                      wbuf[cur][mi], bfrag, acc[mi][ni], 0, 0, 0);
            }
        }
        __syncthreads();   // one barrier per ci-chunk
    }

    // epilogue: co = ch*64 + 16*mi + g*4 + r ; y = r0 + row ; x = 16*ni + l15
    const int y = r0 + row;
#pragma unroll
    for (int mi = 0; mi < 4; ++mi) {
#pragma unroll
        for (int r = 0; r < 4; ++r) {
            int co = ch*64 + 16*mi + g*4 + r;
            float bias = dynb[b*128 + co];
            float* op = out + (((unsigned long long)(b*128 + co))*64 + y)*64;
#pragma unroll
            for (int ni = 0; ni < 4; ++ni)
                op[16*ni + l15] = acc[mi][ni][r] + bias;
        }
    }
}

extern "C" void kernel_launch(void* const* d_in, const int* in_sizes, int n_in,
                              void* d_out, int out_size, void* d_ws, size_t ws_size,
                              hipStream_t stream)
{
    const float* x     = (const float*)d_in[0];
    const float* stats = (const float*)d_in[1];
    const float* W1    = (const float*)d_in[2];
    const float* b1    = (const float*)d_in[3];
    const float* W2    = (const float*)d_in[4];
    const float* b2    = (const float*)d_in[5];
    const float* wexp  = (const float*)d_in[6];
    const float* bexp  = (const float*)d_in[7];
    float* out = (float*)d_out;

    char* ws = (char*)d_ws;
    float* routing        = (float*)ws;                              // 512 B
    float* dynb           = (float*)(ws + 512);                      // 16 KB
    unsigned short* dynw  = (unsigned short*)(ws + 32768);           // 9,437,184 B
    unsigned short* xbfT  = (unsigned short*)(ws + 32768 + 9437184); // 35,684,352 B

    router_kernel<<<1, 64, 0, stream>>>(stats, W1, b1, W2, b2, routing);
    dynw_kernel<<<dim3(128, 4), 256, 0, stream>>>(wexp, bexp, routing, dynw, dynb);
    xcvt_kernel<<<32*66, 256, 0, stream>>>(x, xbfT);
    conv_kernel<<<512, 512, 0, stream>>>(xbfT, dynw, dynb, out);
}

// Round 7
// 87.030 us; speedup vs baseline: 1.1570x; 1.1066x over previous
//
#include <hip/hip_runtime.h>
#include <hip/hip_bf16.h>

// StatDynamicConv2d: routing MLP -> expert-mixed 3x3 conv (per-sample weights)
// B=32, Cin=Cout=128, H=W=64, E=4, K=3, pad=1, stride=1.
//
// ws layout (~45.2 MB):
//   [0,512)                routing[32][4] f32
//   [512, 512+16384)       dynb[32][128] f32
//   [32768, +9437184)      dynw[32][4cic][9tap][8mi][64lane][8] bf16
//                          (MFMA A-fragment order: lane=g*16+l15 holds
//                           co=16*mi+l15, ci=g*8+j of the 32-ci chunk)
//   [9469952, +35684352)   xbfT[32][4cic][66][66][32ci] bf16, halo baked,
//                          16B chunk cg stored at (cg + (lcol>>1))&3

typedef short bf16x8 __attribute__((ext_vector_type(8)));
typedef float f32x4  __attribute__((ext_vector_type(4)));

#define VMWAIT(n) asm volatile("s_waitcnt vmcnt(" #n ")" ::: "memory")

static __device__ __forceinline__ unsigned short f2bf(float f) {
    unsigned u = __float_as_uint(f);
    u = u + 0x7FFFu + ((u >> 16) & 1u);   // round-to-nearest-even
    return (unsigned short)(u >> 16);
}

static __device__ __forceinline__ void gl2lds16(const unsigned short* g, unsigned short* l) {
    __builtin_amdgcn_global_load_lds(
        (const __attribute__((address_space(1))) unsigned int*)g,
        (__attribute__((address_space(3))) unsigned int*)l,
        16, 0, 0);
}

// ---------------- kernel A: router MLP ----------------
__global__ void router_kernel(const float* __restrict__ stats, const float* __restrict__ W1,
                              const float* __restrict__ b1, const float* __restrict__ W2,
                              const float* __restrict__ b2, float* __restrict__ routing)
{
    int t = threadIdx.x;
    if (t >= 32) return;
    float s[6];
#pragma unroll
    for (int i = 0; i < 6; ++i) s[i] = stats[t*6 + i];
    float h[16];
#pragma unroll
    for (int j = 0; j < 16; ++j) {
        float a = b1[j];
#pragma unroll
        for (int i = 0; i < 6; ++i) a += W1[j*6+i]*s[i];
        h[j] = a > 0.f ? a : 0.f;
    }
    float lg[4];
#pragma unroll
    for (int e = 0; e < 4; ++e) {
        float a = b2[e];
#pragma unroll
        for (int j = 0; j < 16; ++j) a += W2[e*16+j]*h[j];
        lg[e] = a;
    }
    float m = fmaxf(fmaxf(lg[0],lg[1]), fmaxf(lg[2],lg[3]));
    float ex[4], sum = 0.f;
#pragma unroll
    for (int e = 0; e < 4; ++e) { ex[e] = expf(lg[e]-m); sum += ex[e]; }
    float inv = 1.f / sum;
#pragma unroll
    for (int e = 0; e < 4; ++e) routing[t*4+e] = ex[e]*inv;
}

// ---------------- kernel B: dynamic weights (bf16, fragment-ordered) + dyn bias ----------------
__global__ void dynw_kernel(const float* __restrict__ wexp, const float* __restrict__ bexp,
                            const float* __restrict__ routing, unsigned short* __restrict__ dynw,
                            float* __restrict__ dynb)
{
    __shared__ float ls[4*1152];
    __shared__ float lr[32*4];
    const int tid = threadIdx.x;
    const int co  = blockIdx.x;
    const int bg  = blockIdx.y;

    for (int i = tid; i < 4*1152; i += 256) {
        int e = i / 1152, j = i - e*1152;
        ls[i] = wexp[((unsigned long long)(e*128 + co))*1152 + j];
    }
    if (tid < 128) lr[tid] = routing[tid];
    __syncthreads();

    if (bg == 0 && tid < 32) {
        float sb = 0.f;
#pragma unroll
        for (int e = 0; e < 4; ++e) sb += lr[tid*4+e] * bexp[e*128 + co];
        dynb[tid*128 + co] = sb;
    }

    const int ci  = tid & 127;
    const int tp0 = tid >> 7;
    const int cic = ci >> 5;
    const int g   = (ci >> 3) & 3;
    const int jj  = ci & 7;
    const int mi  = co >> 4;
    const int l15 = co & 15;
    for (int bb = bg*8; bb < bg*8 + 8; ++bb) {
        float r0 = lr[bb*4+0], r1 = lr[bb*4+1], r2 = lr[bb*4+2], r3 = lr[bb*4+3];
#pragma unroll
        for (int pp = 0; pp < 5; ++pp) {
            int tap = 2*pp + tp0;
            if (tap < 9) {
                int j = ci*9 + tap;
                float v = r0*ls[j] + r1*ls[1152+j] + r2*ls[2*1152+j] + r3*ls[3*1152+j];
                dynw[((((unsigned long long)(bb*4 + cic)*9 + tap)*8 + mi)*64 + g*16 + l15)*8 + jj] = f2bf(v);
            }
        }
    }
}

// ---------------- kernel C: x fp32 -> bf16, transposed + halo + swizzle baked ----------------
// grid 32*66 blocks, 256 threads
__global__ void xcvt_kernel(const float* __restrict__ x, unsigned short* __restrict__ xbfT)
{
    __shared__ unsigned int ls32[64*66];
    const int tid = threadIdx.x;
    const int b  = blockIdx.x / 66;
    const int rr = blockIdx.x - b*66;
    const int gr = rr - 1;

    if (gr < 0 || gr > 63) {
        for (int cic = 0; cic < 4; ++cic) {
            int4* dst = (int4*)(xbfT + ((unsigned long long)((b*4 + cic)*66 + rr))*(66*32));
            for (int d = tid; d < 264; d += 256) dst[d] = make_int4(0,0,0,0);
        }
        return;
    }
    const int lane = tid & 63;
    const int w    = tid >> 6;
#pragma unroll
    for (int k = 0; k < 16; ++k) {
        int cp = w + 4*k;   // ci pair 0..63
        const float* p0 = x + (((unsigned long long)b*128 + 2*cp)*64 + gr)*64 + lane;
        unsigned lo = f2bf(p0[0]);
        unsigned hi = f2bf(p0[64*64]);
        ls32[cp*66 + lane] = lo | (hi << 16);
    }
    __syncthreads();
    for (int d = tid; d < 1056; d += 256) {
        int cic  = d / 264;
        int r    = d - cic*264;
        int lcol = r >> 2;
        int cg   = r & 3;
        int4 v;
        if (lcol == 0 || lcol == 65) {
            v = make_int4(0,0,0,0);
        } else {
            int col  = lcol - 1;
            int base = (cic*16 + cg*4)*66 + col;
            v.x = ls32[base];
            v.y = ls32[base + 66];
            v.z = ls32[base + 2*66];
            v.w = ls32[base + 3*66];
        }
        int p = (cg + (lcol >> 1)) & 3;             // bank-conflict-free swizzle
        int4* dst = (int4*)(xbfT + ((unsigned long long)((b*4 + cic)*66 + rr))*(66*32));
        dst[lcol*4 + p] = v;
    }
}

// ---------------- kernel D: implicit-GEMM conv, bf16 MFMA ----------------
// grid 512 (32 b x 16 4-row tiles), 512 threads (8 waves).
// Wave = (ch = wave&1: cout half, row = wave>>1: output row 0..3).
// Weights staged to LDS (3-deep rotation), counted vmcnt + raw s_barrier
// per step (never vmcnt(0) in steady state). x double-buffered in LDS.
__global__ __launch_bounds__(512, 4) void conv_kernel(
    const unsigned short* __restrict__ xbfT,
    const unsigned short* __restrict__ dynw,
    const float* __restrict__ dynb,
    float* __restrict__ out)
{
    __shared__ __align__(16) unsigned short xs[2][6*66*32];   // 50688 B
    __shared__ __align__(16) unsigned short wsm[3][4096];     // 24576 B

    const int tid  = threadIdx.x;
    const int wave = tid >> 6;
    const int lane = tid & 63;
    const int l15  = lane & 15;
    const int g    = lane >> 4;
    const int ch   = wave & 1;       // cout half (0..1)
    const int row  = wave >> 1;      // output row within tile (0..3)

    // bijective XCD swizzle (512 blocks, 8 XCDs -> 64 contiguous per XCD)
    int bidx = ((blockIdx.x & 7) << 6) | (blockIdx.x >> 3);
    const int b  = bidx >> 4;
    const int r0 = (bidx & 15) << 2;

    f32x4 acc[4][4];
#pragma unroll
    for (int mi = 0; mi < 4; ++mi)
#pragma unroll
        for (int ni = 0; ni < 4; ++ni) acc[mi][ni] = (f32x4){0.f,0.f,0.f,0.f};

    const unsigned short* xsrcb = xbfT + (unsigned long long)b*(4ull*66*66*32);
    const unsigned short* wsrcb = dynw + (unsigned long long)b*(4ull*9*4096);

    // prologue: W(0) -> wsm[0] (1 chunk/thread), xs[0] <- cic 0; full drain once
    gl2lds16(wsrcb + (unsigned)tid*8, wsm[0] + (unsigned)tid*8);
    {
        const unsigned short* src = xsrcb + (unsigned)r0*(66*32);
        for (int c = tid; c < 1584; c += 512) gl2lds16(src + c*8, xs[0] + c*8);
    }
    __syncthreads();

#pragma unroll
    for (int cic = 0; cic < 4; ++cic) {
        const unsigned short* xb = xs[cic & 1];
#pragma unroll
        for (int tap = 0; tap < 9; ++tap) {
            const int s = cic*9 + tap;           // compile-time after unroll
            // A: issue W(s+1) into wsm[(s+1)%3] (distinct from the two
            //    buffers any concurrent reader can touch: s%3, (s-1)%3)
            if (s < 35)
                gl2lds16(wsrcb + (unsigned)((s+1)*4096) + (unsigned)tid*8,
                         wsm[(s+1)%3] + (unsigned)tid*8);
            // B: counted per-wave wait: W(s) landed; newer loads stay in flight.
            //    newer(W(s)) = [3 x-stage loads if step s-1 staged] + [W(s+1)]
            if (s == 1 || s == 10 || s == 19) { VMWAIT(4); }
            else if (s == 35)                 { VMWAIT(0); }
            else if (s > 0)                   { VMWAIT(1); }
            // C: barrier (raw; no counter drain) — all waves' W(s) parts done
            __builtin_amdgcn_s_barrier();
            __builtin_amdgcn_sched_barrier(0);
            // D: stage next ci-chunk (after barrier: prior readers of this
            //    buffer finished before they reached barrier)
            if (tap == 0 && cic < 3) {
                const unsigned short* src = xsrcb + (unsigned)((cic+1)*(66*66*32))
                                          + (unsigned)r0*(66*32);
                unsigned short* dstl = xs[(cic & 1) ^ 1];
                for (int c = tid; c < 1584; c += 512) gl2lds16(src + c*8, dstl + c*8);
            }
            // E: compute from LDS
            const unsigned short* wb = wsm[s % 3];
            const int ky = tap / 3, kx = tap - ky*3;
            const int lrow = row + ky;
            bf16x8 afrag[4];
#pragma unroll
            for (int mi = 0; mi < 4; ++mi)
                afrag[mi] = *(const bf16x8*)(wb + (unsigned)(((ch*4 + mi)*64 + lane)*8));
#pragma unroll
            for (int ni = 0; ni < 4; ++ni) {
                int lcol = 16*ni + l15 + kx;
                int boff = (lrow*66 + lcol)*64 + (((g + (lcol >> 1)) & 3) << 4);
                bf16x8 bfrag = *(const bf16x8*)((const char*)xb + boff);
#pragma unroll
                for (int mi = 0; mi < 4; ++mi)
                    acc[mi][ni] = __builtin_amdgcn_mfma_f32_16x16x32_bf16(
                                      afrag[mi], bfrag, acc[mi][ni], 0, 0, 0);
            }
        }
    }

    // epilogue: co = ch*64 + 16*mi + g*4 + r ; y = r0 + row ; x = 16*ni + l15
    const int y = r0 + row;
#pragma unroll
    for (int mi = 0; mi < 4; ++mi) {
#pragma unroll
        for (int r = 0; r < 4; ++r) {
            int co = ch*64 + 16*mi + g*4 + r;
            float bias = dynb[b*128 + co];
            float* op = out + (((unsigned long long)(b*128 + co))*64 + y)*64;
#pragma unroll
            for (int ni = 0; ni < 4; ++ni)
                op[16*ni + l15] = acc[mi][ni][r] + bias;
        }
    }
}

extern "C" void kernel_launch(void* const* d_in, const int* in_sizes, int n_in,
                              void* d_out, int out_size, void* d_ws, size_t ws_size,
                              hipStream_t stream)
{
    const float* x     = (const float*)d_in[0];
    const float* stats = (const float*)d_in[1];
    const float* W1    = (const float*)d_in[2];
    const float* b1    = (const float*)d_in[3];
    const float* W2    = (const float*)d_in[4];
    const float* b2    = (const float*)d_in[5];
    const float* wexp  = (const float*)d_in[6];
    const float* bexp  = (const float*)d_in[7];
    float* out = (float*)d_out;

    char* ws = (char*)d_ws;
    float* routing        = (float*)ws;                              // 512 B
    float* dynb           = (float*)(ws + 512);                      // 16 KB
    unsigned short* dynw  = (unsigned short*)(ws + 32768);           // 9,437,184 B
    unsigned short* xbfT  = (unsigned short*)(ws + 32768 + 9437184); // 35,684,352 B

    router_kernel<<<1, 64, 0, stream>>>(stats, W1, b1, W2, b2, routing);
    dynw_kernel<<<dim3(128, 4), 256, 0, stream>>>(wexp, bexp, routing, dynw, dynb);
    xcvt_kernel<<<32*66, 256, 0, stream>>>(x, xbfT);
    conv_kernel<<<512, 512, 0, stream>>>(xbfT, dynw, dynb, out);
}

// Round 8
// 76.084 us; speedup vs baseline: 1.3235x; 1.1439x over previous
//
#include <hip/hip_runtime.h>
#include <hip/hip_bf16.h>

// StatDynamicConv2d: routing MLP -> expert-mixed 3x3 conv (per-sample weights)
// B=32, Cin=Cout=128, H=W=64, E=4, K=3, pad=1, stride=1.
//
// ws layout (~45.2 MB):
//   [0,512)                routing[32][4] f32
//   [512, 512+16384)       dynb[32][128] f32
//   [32768, +9437184)      dynw[32][4cic][9tap][8mi][64lane][8] bf16
//                          (MFMA A-fragment order: lane=g*16+l15 holds
//                           co=16*mi+l15, ci=g*8+j of the 32-ci chunk)
//   [9469952, +35684352)   xbfT[32][4cic][66][66][32ci] bf16, halo baked,
//                          16B chunk cg stored at (cg + (lcol>>1))&3

typedef short bf16x8 __attribute__((ext_vector_type(8)));
typedef float f32x4  __attribute__((ext_vector_type(4)));

#define VMWAIT(n) asm volatile("s_waitcnt vmcnt(" #n ")" ::: "memory")

static __device__ __forceinline__ unsigned short f2bf(float f) {
    unsigned u = __float_as_uint(f);
    u = u + 0x7FFFu + ((u >> 16) & 1u);   // round-to-nearest-even
    return (unsigned short)(u >> 16);
}

static __device__ __forceinline__ void gl2lds16(const unsigned short* g, unsigned short* l) {
    __builtin_amdgcn_global_load_lds(
        (const __attribute__((address_space(1))) unsigned int*)g,
        (__attribute__((address_space(3))) unsigned int*)l,
        16, 0, 0);
}

// ---------------- kernel A: router MLP ----------------
__global__ void router_kernel(const float* __restrict__ stats, const float* __restrict__ W1,
                              const float* __restrict__ b1, const float* __restrict__ W2,
                              const float* __restrict__ b2, float* __restrict__ routing)
{
    int t = threadIdx.x;
    if (t >= 32) return;
    float s[6];
#pragma unroll
    for (int i = 0; i < 6; ++i) s[i] = stats[t*6 + i];
    float h[16];
#pragma unroll
    for (int j = 0; j < 16; ++j) {
        float a = b1[j];
#pragma unroll
        for (int i = 0; i < 6; ++i) a += W1[j*6+i]*s[i];
        h[j] = a > 0.f ? a : 0.f;
    }
    float lg[4];
#pragma unroll
    for (int e = 0; e < 4; ++e) {
        float a = b2[e];
#pragma unroll
        for (int j = 0; j < 16; ++j) a += W2[e*16+j]*h[j];
        lg[e] = a;
    }
    float m = fmaxf(fmaxf(lg[0],lg[1]), fmaxf(lg[2],lg[3]));
    float ex[4], sum = 0.f;
#pragma unroll
    for (int e = 0; e < 4; ++e) { ex[e] = expf(lg[e]-m); sum += ex[e]; }
    float inv = 1.f / sum;
#pragma unroll
    for (int e = 0; e < 4; ++e) routing[t*4+e] = ex[e]*inv;
}

// ---------------- kernel B: dynamic weights (bf16, fragment-ordered) + dyn bias ----------------
__global__ void dynw_kernel(const float* __restrict__ wexp, const float* __restrict__ bexp,
                            const float* __restrict__ routing, unsigned short* __restrict__ dynw,
                            float* __restrict__ dynb)
{
    __shared__ float ls[4*1152];
    __shared__ float lr[32*4];
    const int tid = threadIdx.x;
    const int co  = blockIdx.x;
    const int bg  = blockIdx.y;

    for (int i = tid; i < 4*1152; i += 256) {
        int e = i / 1152, j = i - e*1152;
        ls[i] = wexp[((unsigned long long)(e*128 + co))*1152 + j];
    }
    if (tid < 128) lr[tid] = routing[tid];
    __syncthreads();

    if (bg == 0 && tid < 32) {
        float sb = 0.f;
#pragma unroll
        for (int e = 0; e < 4; ++e) sb += lr[tid*4+e] * bexp[e*128 + co];
        dynb[tid*128 + co] = sb;
    }

    const int ci  = tid & 127;
    const int tp0 = tid >> 7;
    const int cic = ci >> 5;
    const int g   = (ci >> 3) & 3;
    const int jj  = ci & 7;
    const int mi  = co >> 4;
    const int l15 = co & 15;
    for (int bb = bg*8; bb < bg*8 + 8; ++bb) {
        float r0 = lr[bb*4+0], r1 = lr[bb*4+1], r2 = lr[bb*4+2], r3 = lr[bb*4+3];
#pragma unroll
        for (int pp = 0; pp < 5; ++pp) {
            int tap = 2*pp + tp0;
            if (tap < 9) {
                int j = ci*9 + tap;
                float v = r0*ls[j] + r1*ls[1152+j] + r2*ls[2*1152+j] + r3*ls[3*1152+j];
                dynw[((((unsigned long long)(bb*4 + cic)*9 + tap)*8 + mi)*64 + g*16 + l15)*8 + jj] = f2bf(v);
            }
        }
    }
}

// ---------------- kernel C: x fp32 -> bf16, transposed + halo + swizzle baked ----------------
// grid 32*66 blocks, 256 threads
__global__ void xcvt_kernel(const float* __restrict__ x, unsigned short* __restrict__ xbfT)
{
    __shared__ unsigned int ls32[64*66];
    const int tid = threadIdx.x;
    const int b  = blockIdx.x / 66;
    const int rr = blockIdx.x - b*66;
    const int gr = rr - 1;

    if (gr < 0 || gr > 63) {
        for (int cic = 0; cic < 4; ++cic) {
            int4* dst = (int4*)(xbfT + ((unsigned long long)((b*4 + cic)*66 + rr))*(66*32));
            for (int d = tid; d < 264; d += 256) dst[d] = make_int4(0,0,0,0);
        }
        return;
    }
    const int lane = tid & 63;
    const int w    = tid >> 6;
#pragma unroll
    for (int k = 0; k < 16; ++k) {
        int cp = w + 4*k;   // ci pair 0..63
        const float* p0 = x + (((unsigned long long)b*128 + 2*cp)*64 + gr)*64 + lane;
        unsigned lo = f2bf(p0[0]);
        unsigned hi = f2bf(p0[64*64]);
        ls32[cp*66 + lane] = lo | (hi << 16);
    }
    __syncthreads();
    for (int d = tid; d < 1056; d += 256) {
        int cic  = d / 264;
        int r    = d - cic*264;
        int lcol = r >> 2;
        int cg   = r & 3;
        int4 v;
        if (lcol == 0 || lcol == 65) {
            v = make_int4(0,0,0,0);
        } else {
            int col  = lcol - 1;
            int base = (cic*16 + cg*4)*66 + col;
            v.x = ls32[base];
            v.y = ls32[base + 66];
            v.z = ls32[base + 2*66];
            v.w = ls32[base + 3*66];
        }
        int p = (cg + (lcol >> 1)) & 3;             // bank-conflict-free swizzle
        int4* dst = (int4*)(xbfT + ((unsigned long long)((b*4 + cic)*66 + rr))*(66*32));
        dst[lcol*4 + p] = v;
    }
}

// ---------------- kernel D: implicit-GEMM conv, bf16 MFMA ----------------
// grid 512 (32 b x 16 4-row tiles), 256 threads (4 waves), wave = 1 output
// row x full 128 co (mi=8; acc 128 regs, fits 256-cap at 2 waves/SIMD -> no
// spill). Weights staged to LDS (3-deep rotation), counted vmcnt + raw
// s_barrier per step (never vmcnt(0) in steady state). x double-buffered.
__global__ __launch_bounds__(256, 2) void conv_kernel(
    const unsigned short* __restrict__ xbfT,
    const unsigned short* __restrict__ dynw,
    const float* __restrict__ dynb,
    float* __restrict__ out)
{
    __shared__ __align__(16) unsigned short xs[2][6*66*32];   // 50688 B
    __shared__ __align__(16) unsigned short wsm[3][4096];     // 24576 B

    const int tid  = threadIdx.x;
    const int wave = tid >> 6;       // output row within tile (0..3)
    const int lane = tid & 63;
    const int l15  = lane & 15;
    const int g    = lane >> 4;

    // bijective XCD swizzle (512 blocks, 8 XCDs -> 64 contiguous per XCD)
    int bidx = ((blockIdx.x & 7) << 6) | (blockIdx.x >> 3);
    const int b  = bidx >> 4;
    const int r0 = (bidx & 15) << 2;

    f32x4 acc[8][4];
#pragma unroll
    for (int mi = 0; mi < 8; ++mi)
#pragma unroll
        for (int ni = 0; ni < 4; ++ni) acc[mi][ni] = (f32x4){0.f,0.f,0.f,0.f};

    const unsigned short* xsrcb = xbfT + (unsigned long long)b*(4ull*66*66*32);
    const unsigned short* wsrcb = dynw + (unsigned long long)b*(4ull*9*4096);

    // prologue: W(0) -> wsm[0] (2 chunks/thread), xs[0] <- cic 0; full drain once
    gl2lds16(wsrcb + (unsigned)tid*8,         wsm[0] + (unsigned)tid*8);
    gl2lds16(wsrcb + (unsigned)(tid+256)*8,   wsm[0] + (unsigned)(tid+256)*8);
    {
        const unsigned short* src = xsrcb + (unsigned)r0*(66*32);
        for (int c = tid; c < 1584; c += 256) gl2lds16(src + c*8, xs[0] + c*8);
    }
    __syncthreads();

#pragma unroll
    for (int cic = 0; cic < 4; ++cic) {
        const unsigned short* xb = xs[cic & 1];
#pragma unroll
        for (int tap = 0; tap < 9; ++tap) {
            const int s = cic*9 + tap;           // compile-time after unroll
            // A: issue W(s+1) into wsm[(s+1)%3] (distinct from the two
            //    buffers any concurrent reader can touch: s%3, (s-1)%3)
            if (s < 35) {
                const unsigned short* wsrc = wsrcb + (unsigned)((s+1)*4096);
                unsigned short* wd = wsm[(s+1)%3];
                gl2lds16(wsrc + (unsigned)tid*8,       wd + (unsigned)tid*8);
                gl2lds16(wsrc + (unsigned)(tid+256)*8, wd + (unsigned)(tid+256)*8);
            }
            // B: counted per-wave wait: W(s) (2 chunks) landed; newer loads
            //    stay in flight. newer(W(s)) = [6-7 xs loads if step s-1
            //    staged] + [W(s+1) = 2]
            if (s == 1 || s == 10 || s == 19) { VMWAIT(8); }
            else if (s == 35)                 { VMWAIT(0); }
            else if (s > 0)                   { VMWAIT(2); }
            // C: barrier (raw; no counter drain) — all waves' W(s) parts done
            __builtin_amdgcn_s_barrier();
            __builtin_amdgcn_sched_barrier(0);
            // D: stage next ci-chunk (after barrier: prior readers of this
            //    buffer finished before they reached the barrier)
            if (tap == 0 && cic < 3) {
                const unsigned short* src = xsrcb + (unsigned)((cic+1)*(66*66*32))
                                          + (unsigned)r0*(66*32);
                unsigned short* dstl = xs[(cic & 1) ^ 1];
                for (int c = tid; c < 1584; c += 256) gl2lds16(src + c*8, dstl + c*8);
            }
            // E: compute from LDS: 8 afrag reads, then 4 x (1 bfrag + 8 MFMA)
            const unsigned short* wb = wsm[s % 3];
            const int ky = tap / 3, kx = tap - ky*3;
            const int lrow = wave + ky;
            bf16x8 afrag[8];
#pragma unroll
            for (int mi = 0; mi < 8; ++mi)
                afrag[mi] = *(const bf16x8*)(wb + (unsigned)((mi*64 + lane)*8));
#pragma unroll
            for (int ni = 0; ni < 4; ++ni) {
                int lcol = 16*ni + l15 + kx;
                int boff = (lrow*66 + lcol)*64 + (((g + (lcol >> 1)) & 3) << 4);
                bf16x8 bfrag = *(const bf16x8*)((const char*)xb + boff);
#pragma unroll
                for (int mi = 0; mi < 8; ++mi)
                    acc[mi][ni] = __builtin_amdgcn_mfma_f32_16x16x32_bf16(
                                      afrag[mi], bfrag, acc[mi][ni], 0, 0, 0);
            }
        }
    }

    // epilogue: co = 16*mi + g*4 + r ; y = r0 + wave ; x = 16*ni + l15
    const int y = r0 + wave;
#pragma unroll
    for (int mi = 0; mi < 8; ++mi) {
#pragma unroll
        for (int r = 0; r < 4; ++r) {
            int co = 16*mi + g*4 + r;
            float bias = dynb[b*128 + co];
            float* op = out + (((unsigned long long)(b*128 + co))*64 + y)*64;
#pragma unroll
            for (int ni = 0; ni < 4; ++ni)
                op[16*ni + l15] = acc[mi][ni][r] + bias;
        }
    }
}

extern "C" void kernel_launch(void* const* d_in, const int* in_sizes, int n_in,
                              void* d_out, int out_size, void* d_ws, size_t ws_size,
                              hipStream_t stream)
{
    const float* x     = (const float*)d_in[0];
    const float* stats = (const float*)d_in[1];
    const float* W1    = (const float*)d_in[2];
    const float* b1    = (const float*)d_in[3];
    const float* W2    = (const float*)d_in[4];
    const float* b2    = (const float*)d_in[5];
    const float* wexp  = (const float*)d_in[6];
    const float* bexp  = (const float*)d_in[7];
    float* out = (float*)d_out;

    char* ws = (char*)d_ws;
    float* routing        = (float*)ws;                              // 512 B
    float* dynb           = (float*)(ws + 512);                      // 16 KB
    unsigned short* dynw  = (unsigned short*)(ws + 32768);           // 9,437,184 B
    unsigned short* xbfT  = (unsigned short*)(ws + 32768 + 9437184); // 35,684,352 B

    router_kernel<<<1, 64, 0, stream>>>(stats, W1, b1, W2, b2, routing);
    dynw_kernel<<<dim3(128, 4), 256, 0, stream>>>(wexp, bexp, routing, dynw, dynb);
    xcvt_kernel<<<32*66, 256, 0, stream>>>(x, xbfT);
    conv_kernel<<<512, 256, 0, stream>>>(xbfT, dynw, dynb, out);
}

// Round 9
// 70.381 us; speedup vs baseline: 1.4307x; 1.0810x over previous
//
#include <hip/hip_runtime.h>
#include <hip/hip_bf16.h>

// StatDynamicConv2d: routing MLP -> expert-mixed 3x3 conv (per-sample weights)
// B=32, Cin=Cout=128, H=W=64, E=4, K=3, pad=1, stride=1.
//
// ws layout (~45.2 MB):
//   [0,512)                (unused)
//   [512, 512+16384)       dynb[32][128] f32
//   [32768, +9437184)      dynw[32][4cic][9tap][8mi][64lane][8] bf16
//                          (MFMA A-fragment order: lane=g*16+l15 holds
//                           co=16*mi+l15, ci=g*8+j of the 32-ci chunk)
//   [9469952, +35684352)   xbfT[32][4cic][66][66][32ci] bf16, halo baked,
//                          16B chunk cg stored at (cg + (lcol>>1))&3

typedef short bf16x8 __attribute__((ext_vector_type(8)));
typedef float f32x4  __attribute__((ext_vector_type(4)));

#define VMWAIT(n) asm volatile("s_waitcnt vmcnt(" #n ")" ::: "memory")

static __device__ __forceinline__ unsigned short f2bf(float f) {
    unsigned u = __float_as_uint(f);
    u = u + 0x7FFFu + ((u >> 16) & 1u);   // round-to-nearest-even
    return (unsigned short)(u >> 16);
}

static __device__ __forceinline__ void gl2lds16(const unsigned short* g, unsigned short* l) {
    __builtin_amdgcn_global_load_lds(
        (const __attribute__((address_space(1))) unsigned int*)g,
        (__attribute__((address_space(3))) unsigned int*)l,
        16, 0, 0);
}

// ---------------- kernel P: fused prep (xcvt + router + dynw) ----------------
// grid 2624 = 2112 xcvt blocks + 512 dynw blocks, 256 threads
__global__ void prep_kernel(const float* __restrict__ x, unsigned short* __restrict__ xbfT,
                            const float* __restrict__ stats, const float* __restrict__ W1,
                            const float* __restrict__ b1, const float* __restrict__ W2,
                            const float* __restrict__ b2, const float* __restrict__ wexp,
                            const float* __restrict__ bexp, unsigned short* __restrict__ dynw,
                            float* __restrict__ dynb)
{
    __shared__ float smem[4*1152 + 128];    // ls(f32) / lr ; xcvt aliases ls32 on top
    const int tid = threadIdx.x;

    if (blockIdx.x < 2112) {
        // ---------- xcvt: x fp32 -> bf16, transposed + halo + swizzle baked ----------
        unsigned int* ls32 = (unsigned int*)smem;     // 64*66 uints = 16896 B
        const int b  = blockIdx.x / 66;
        const int rr = blockIdx.x - b*66;
        const int gr = rr - 1;

        if (gr < 0 || gr > 63) {
            for (int cic = 0; cic < 4; ++cic) {
                int4* dst = (int4*)(xbfT + ((unsigned long long)((b*4 + cic)*66 + rr))*(66*32));
                for (int d = tid; d < 264; d += 256) dst[d] = make_int4(0,0,0,0);
            }
            return;
        }
        const int lane = tid & 63;
        const int w    = tid >> 6;
#pragma unroll
        for (int k = 0; k < 16; ++k) {
            int cp = w + 4*k;   // ci pair 0..63
            const float* p0 = x + (((unsigned long long)b*128 + 2*cp)*64 + gr)*64 + lane;
            unsigned lo = f2bf(p0[0]);
            unsigned hi = f2bf(p0[64*64]);
            ls32[cp*66 + lane] = lo | (hi << 16);
        }
        __syncthreads();
        for (int d = tid; d < 1056; d += 256) {
            int cic  = d / 264;
            int r    = d - cic*264;
            int lcol = r >> 2;
            int cg   = r & 3;
            int4 v;
            if (lcol == 0 || lcol == 65) {
                v = make_int4(0,0,0,0);
            } else {
                int col  = lcol - 1;
                int base = (cic*16 + cg*4)*66 + col;
                v.x = ls32[base];
                v.y = ls32[base + 66];
                v.z = ls32[base + 2*66];
                v.w = ls32[base + 3*66];
            }
            int p = (cg + (lcol >> 1)) & 3;             // bank-conflict-free swizzle
            int4* dst = (int4*)(xbfT + ((unsigned long long)((b*4 + cic)*66 + rr))*(66*32));
            dst[lcol*4 + p] = v;
        }
        return;
    }

    // ---------- dynw (+ inline router): expert mix -> bf16 fragment layout ----------
    const int bid2 = blockIdx.x - 2112;
    const int co   = bid2 & 127;
    const int bg   = bid2 >> 7;
    float* ls = smem;                 // 4*1152 floats
    float* lr = smem + 4*1152;        // 32*4 routing

    if (tid < 32) {                   // recompute tiny router MLP per block (cheap)
        float s[6];
#pragma unroll
        for (int i = 0; i < 6; ++i) s[i] = stats[tid*6 + i];
        float h[16];
#pragma unroll
        for (int j = 0; j < 16; ++j) {
            float a = b1[j];
#pragma unroll
            for (int i = 0; i < 6; ++i) a += W1[j*6+i]*s[i];
            h[j] = a > 0.f ? a : 0.f;
        }
        float lg[4];
#pragma unroll
        for (int e = 0; e < 4; ++e) {
            float a = b2[e];
#pragma unroll
            for (int j = 0; j < 16; ++j) a += W2[e*16+j]*h[j];
            lg[e] = a;
        }
        float m = fmaxf(fmaxf(lg[0],lg[1]), fmaxf(lg[2],lg[3]));
        float ex[4], sum = 0.f;
#pragma unroll
        for (int e = 0; e < 4; ++e) { ex[e] = expf(lg[e]-m); sum += ex[e]; }
        float inv = 1.f / sum;
#pragma unroll
        for (int e = 0; e < 4; ++e) lr[tid*4+e] = ex[e]*inv;
    }
    for (int i = tid; i < 4*1152; i += 256) {
        int e = i / 1152, j = i - e*1152;
        ls[i] = wexp[((unsigned long long)(e*128 + co))*1152 + j];
    }
    __syncthreads();

    if (bg == 0 && tid < 32) {
        float sb = 0.f;
#pragma unroll
        for (int e = 0; e < 4; ++e) sb += lr[tid*4+e] * bexp[e*128 + co];
        dynb[tid*128 + co] = sb;
    }

    const int ci  = tid & 127;
    const int tp0 = tid >> 7;
    const int cic = ci >> 5;
    const int g   = (ci >> 3) & 3;
    const int jj  = ci & 7;
    const int mi  = co >> 4;
    const int l15 = co & 15;
    for (int bb = bg*8; bb < bg*8 + 8; ++bb) {
        float r0 = lr[bb*4+0], r1 = lr[bb*4+1], r2 = lr[bb*4+2], r3 = lr[bb*4+3];
#pragma unroll
        for (int pp = 0; pp < 5; ++pp) {
            int tap = 2*pp + tp0;
            if (tap < 9) {
                int j = ci*9 + tap;
                float v = r0*ls[j] + r1*ls[1152+j] + r2*ls[2*1152+j] + r3*ls[3*1152+j];
                dynw[((((unsigned long long)(bb*4 + cic)*9 + tap)*8 + mi)*64 + g*16 + l15)*8 + jj] = f2bf(v);
            }
        }
    }
}

// ---------------- kernel D: implicit-GEMM conv, bf16 MFMA ----------------
// grid 512 (32 b x 16 4-row tiles), 256 threads (4 waves), wave = 1 output
// row x full 128 co (mi=8). Weights staged to LDS, 6-deep rotation, ONE
// vmcnt(0)+s_barrier per 3-tap phase (12 phases); W-issue post-barrier so
// rotation disjointness is exact. x double-buffered across cic.
__global__ __launch_bounds__(256, 2) void conv_kernel(
    const unsigned short* __restrict__ xbfT,
    const unsigned short* __restrict__ dynw,
    const float* __restrict__ dynb,
    float* __restrict__ out)
{
    __shared__ __align__(16) unsigned short xs[2][6*66*32];   // 50688 B
    __shared__ __align__(16) unsigned short wsm[6][4096];     // 24576 B

    const int tid  = threadIdx.x;
    const int wave = tid >> 6;       // output row within tile (0..3)
    const int lane = tid & 63;
    const int l15  = lane & 15;
    const int g    = lane >> 4;

    // bijective XCD swizzle (512 blocks, 8 XCDs -> 64 contiguous per XCD)
    int bidx = ((blockIdx.x & 7) << 6) | (blockIdx.x >> 3);
    const int b  = bidx >> 4;
    const int r0 = (bidx & 15) << 2;

    f32x4 acc[8][4];
#pragma unroll
    for (int mi = 0; mi < 8; ++mi)
#pragma unroll
        for (int ni = 0; ni < 4; ++ni) acc[mi][ni] = (f32x4){0.f,0.f,0.f,0.f};

    const unsigned short* xsrcb = xbfT + (unsigned long long)b*(4ull*66*66*32);
    const unsigned short* wsrcb = dynw + (unsigned long long)b*(4ull*9*4096);

    // prologue: W(0..2) -> wsm[0..2], xs[0] <- cic 0; full drain once
#pragma unroll
    for (int k = 0; k < 3; ++k) {
        const unsigned short* wsrc = wsrcb + (unsigned)(k*4096);
        gl2lds16(wsrc + (unsigned)tid*8,       wsm[k] + (unsigned)tid*8);
        gl2lds16(wsrc + (unsigned)(tid+256)*8, wsm[k] + (unsigned)(tid+256)*8);
    }
    {
        const unsigned short* src = xsrcb + (unsigned)r0*(66*32);
        for (int c = tid; c < 1584; c += 256) gl2lds16(src + c*8, xs[0] + c*8);
    }
    __syncthreads();

#pragma unroll
    for (int p = 0; p < 12; ++p) {
        const int cic = p / 3;
        if (p > 0) {
            // everything in flight was issued >= 1 full phase ago -> cheap drain
            VMWAIT(0);
            __builtin_amdgcn_s_barrier();
            __builtin_amdgcn_sched_barrier(0);
        }
        // issue next phase's 3 weight tiles (post-barrier: rotation-safe).
        // reads this phase touch wsm[(3p..3p+2)%6]; writes wsm[(3p+3..3p+5)%6].
        if (p < 11) {
#pragma unroll
            for (int k = 0; k < 3; ++k) {
                const int s = 3*p + 3 + k;
                const unsigned short* wsrc = wsrcb + (unsigned)(s*4096);
                unsigned short* wd = wsm[s % 6];
                gl2lds16(wsrc + (unsigned)tid*8,       wd + (unsigned)tid*8);
                gl2lds16(wsrc + (unsigned)(tid+256)*8, wd + (unsigned)(tid+256)*8);
            }
        }
        // stage next ci-chunk at each cic's first phase (post-barrier: prior
        // readers of the target buffer are provably done)
        if ((p % 3) == 0 && cic < 3) {
            const unsigned short* src = xsrcb + (unsigned)((cic+1)*(66*66*32))
                                      + (unsigned)r0*(66*32);
            unsigned short* dstl = xs[(cic & 1) ^ 1];
            for (int c = tid; c < 1584; c += 256) gl2lds16(src + c*8, dstl + c*8);
        }
        // compute 3 taps (ky = p%3, kx = 0..2) with no intervening sync
        const unsigned short* xb = xs[cic & 1];
        const int ky   = p % 3;
        const int lrow = wave + ky;
        __builtin_amdgcn_s_setprio(1);
#pragma unroll
        for (int kx = 0; kx < 3; ++kx) {
            const unsigned short* wb = wsm[(3*p + kx) % 6];
            bf16x8 afrag[8];
#pragma unroll
            for (int mi = 0; mi < 8; ++mi)
                afrag[mi] = *(const bf16x8*)(wb + (unsigned)((mi*64 + lane)*8));
#pragma unroll
            for (int ni = 0; ni < 4; ++ni) {
                int lcol = 16*ni + l15 + kx;
                int boff = (lrow*66 + lcol)*64 + (((g + (lcol >> 1)) & 3) << 4);
                bf16x8 bfrag = *(const bf16x8*)((const char*)xb + boff);
#pragma unroll
                for (int mi = 0; mi < 8; ++mi)
                    acc[mi][ni] = __builtin_amdgcn_mfma_f32_16x16x32_bf16(
                                      afrag[mi], bfrag, acc[mi][ni], 0, 0, 0);
            }
        }
        __builtin_amdgcn_s_setprio(0);
    }

    // epilogue: co = 16*mi + g*4 + r ; y = r0 + wave ; x = 16*ni + l15
    const int y = r0 + wave;
#pragma unroll
    for (int mi = 0; mi < 8; ++mi) {
#pragma unroll
        for (int r = 0; r < 4; ++r) {
            int co = 16*mi + g*4 + r;
            float bias = dynb[b*128 + co];
            float* op = out + (((unsigned long long)(b*128 + co))*64 + y)*64;
#pragma unroll
            for (int ni = 0; ni < 4; ++ni)
                op[16*ni + l15] = acc[mi][ni][r] + bias;
        }
    }
}

extern "C" void kernel_launch(void* const* d_in, const int* in_sizes, int n_in,
                              void* d_out, int out_size, void* d_ws, size_t ws_size,
                              hipStream_t stream)
{
    const float* x     = (const float*)d_in[0];
    const float* stats = (const float*)d_in[1];
    const float* W1    = (const float*)d_in[2];
    const float* b1    = (const float*)d_in[3];
    const float* W2    = (const float*)d_in[4];
    const float* b2    = (const float*)d_in[5];
    const float* wexp  = (const float*)d_in[6];
    const float* bexp  = (const float*)d_in[7];
    float* out = (float*)d_out;

    char* ws = (char*)d_ws;
    float* dynb           = (float*)(ws + 512);                      // 16 KB
    unsigned short* dynw  = (unsigned short*)(ws + 32768);           // 9,437,184 B
    unsigned short* xbfT  = (unsigned short*)(ws + 32768 + 9437184); // 35,684,352 B

    prep_kernel<<<2624, 256, 0, stream>>>(x, xbfT, stats, W1, b1, W2, b2,
                                          wexp, bexp, dynw, dynb);
    conv_kernel<<<512, 256, 0, stream>>>(xbfT, dynw, dynb, out);
}

// Round 10
// 65.665 us; speedup vs baseline: 1.5335x; 1.0718x over previous
//
#include <hip/hip_runtime.h>
#include <hip/hip_bf16.h>

// StatDynamicConv2d: routing MLP -> expert-mixed 3x3 conv (per-sample weights)
// B=32, Cin=Cout=128, H=W=64, E=4, K=3, pad=1, stride=1.
//
// ws layout (~45.2 MB):
//   [0,512)                (unused)
//   [512, 512+16384)       dynb[32][128] f32
//   [32768, +9437184)      dynw[32][4cic][9tap][8mi][64lane][8] bf16
//                          (MFMA A-fragment order: lane=g*16+l15 holds
//                           co=16*mi+l15, ci=g*8+j of the 32-ci chunk)
//   [9469952, +35684352)   xbfT[32][4cic][66][66][32ci] bf16, halo baked,
//                          16B chunk cg stored at (cg + (lcol>>1))&3

typedef short bf16x8 __attribute__((ext_vector_type(8)));
typedef float f32x4  __attribute__((ext_vector_type(4)));

#define VMWAIT(n) asm volatile("s_waitcnt vmcnt(" #n ")" ::: "memory")

static __device__ __forceinline__ unsigned short f2bf(float f) {
    unsigned u = __float_as_uint(f);
    u = u + 0x7FFFu + ((u >> 16) & 1u);   // round-to-nearest-even
    return (unsigned short)(u >> 16);
}

static __device__ __forceinline__ void gl2lds16(const unsigned short* g, unsigned short* l) {
    __builtin_amdgcn_global_load_lds(
        (const __attribute__((address_space(1))) unsigned int*)g,
        (__attribute__((address_space(3))) unsigned int*)l,
        16, 0, 0);
}

// ---------------- kernel P: fused prep (xcvt + router + dynw) ----------------
// grid 2624 = 2112 xcvt blocks + 512 dynw blocks, 256 threads
__global__ void prep_kernel(const float* __restrict__ x, unsigned short* __restrict__ xbfT,
                            const float* __restrict__ stats, const float* __restrict__ W1,
                            const float* __restrict__ b1, const float* __restrict__ W2,
                            const float* __restrict__ b2, const float* __restrict__ wexp,
                            const float* __restrict__ bexp, unsigned short* __restrict__ dynw,
                            float* __restrict__ dynb)
{
    __shared__ float smem[4*1152 + 128];    // ls(f32) / lr ; xcvt aliases ls32 on top
    const int tid = threadIdx.x;

    if (blockIdx.x < 2112) {
        // ---------- xcvt: x fp32 -> bf16, transposed + halo + swizzle baked ----------
        unsigned int* ls32 = (unsigned int*)smem;     // 64*66 uints = 16896 B
        const int b  = blockIdx.x / 66;
        const int rr = blockIdx.x - b*66;
        const int gr = rr - 1;

        if (gr < 0 || gr > 63) {
            for (int cic = 0; cic < 4; ++cic) {
                int4* dst = (int4*)(xbfT + ((unsigned long long)((b*4 + cic)*66 + rr))*(66*32));
                for (int d = tid; d < 264; d += 256) dst[d] = make_int4(0,0,0,0);
            }
            return;
        }
        const int lane = tid & 63;
        const int w    = tid >> 6;
#pragma unroll
        for (int k = 0; k < 16; ++k) {
            int cp = w + 4*k;   // ci pair 0..63
            const float* p0 = x + (((unsigned long long)b*128 + 2*cp)*64 + gr)*64 + lane;
            unsigned lo = f2bf(p0[0]);
            unsigned hi = f2bf(p0[64*64]);
            ls32[cp*66 + lane] = lo | (hi << 16);
        }
        __syncthreads();
        for (int d = tid; d < 1056; d += 256) {
            int cic  = d / 264;
            int r    = d - cic*264;
            int lcol = r >> 2;
            int cg   = r & 3;
            int4 v;
            if (lcol == 0 || lcol == 65) {
                v = make_int4(0,0,0,0);
            } else {
                int col  = lcol - 1;
                int base = (cic*16 + cg*4)*66 + col;
                v.x = ls32[base];
                v.y = ls32[base + 66];
                v.z = ls32[base + 2*66];
                v.w = ls32[base + 3*66];
            }
            int p = (cg + (lcol >> 1)) & 3;             // bank-conflict-free swizzle
            int4* dst = (int4*)(xbfT + ((unsigned long long)((b*4 + cic)*66 + rr))*(66*32));
            dst[lcol*4 + p] = v;
        }
        return;
    }

    // ---------- dynw (+ inline router): expert mix -> bf16 fragment layout ----------
    const int bid2 = blockIdx.x - 2112;
    const int co   = bid2 & 127;
    const int bg   = bid2 >> 7;
    float* ls = smem;                 // 4*1152 floats
    float* lr = smem + 4*1152;        // 32*4 routing

    if (tid < 32) {                   // recompute tiny router MLP per block (cheap)
        float s[6];
#pragma unroll
        for (int i = 0; i < 6; ++i) s[i] = stats[tid*6 + i];
        float h[16];
#pragma unroll
        for (int j = 0; j < 16; ++j) {
            float a = b1[j];
#pragma unroll
            for (int i = 0; i < 6; ++i) a += W1[j*6+i]*s[i];
            h[j] = a > 0.f ? a : 0.f;
        }
        float lg[4];
#pragma unroll
        for (int e = 0; e < 4; ++e) {
            float a = b2[e];
#pragma unroll
            for (int j = 0; j < 16; ++j) a += W2[e*16+j]*h[j];
            lg[e] = a;
        }
        float m = fmaxf(fmaxf(lg[0],lg[1]), fmaxf(lg[2],lg[3]));
        float ex[4], sum = 0.f;
#pragma unroll
        for (int e = 0; e < 4; ++e) { ex[e] = expf(lg[e]-m); sum += ex[e]; }
        float inv = 1.f / sum;
#pragma unroll
        for (int e = 0; e < 4; ++e) lr[tid*4+e] = ex[e]*inv;
    }
    for (int i = tid; i < 4*1152; i += 256) {
        int e = i / 1152, j = i - e*1152;
        ls[i] = wexp[((unsigned long long)(e*128 + co))*1152 + j];
    }
    __syncthreads();

    if (bg == 0 && tid < 32) {
        float sb = 0.f;
#pragma unroll
        for (int e = 0; e < 4; ++e) sb += lr[tid*4+e] * bexp[e*128 + co];
        dynb[tid*128 + co] = sb;
    }

    const int ci  = tid & 127;
    const int tp0 = tid >> 7;
    const int cic = ci >> 5;
    const int g   = (ci >> 3) & 3;
    const int jj  = ci & 7;
    const int mi  = co >> 4;
    const int l15 = co & 15;
    for (int bb = bg*8; bb < bg*8 + 8; ++bb) {
        float r0 = lr[bb*4+0], r1 = lr[bb*4+1], r2 = lr[bb*4+2], r3 = lr[bb*4+3];
#pragma unroll
        for (int pp = 0; pp < 5; ++pp) {
            int tap = 2*pp + tp0;
            if (tap < 9) {
                int j = ci*9 + tap;
                float v = r0*ls[j] + r1*ls[1152+j] + r2*ls[2*1152+j] + r3*ls[3*1152+j];
                dynw[((((unsigned long long)(bb*4 + cic)*9 + tap)*8 + mi)*64 + g*16 + l15)*8 + jj] = f2bf(v);
            }
        }
    }
}

// ---------------- kernel D: implicit-GEMM conv, bf16 MFMA ----------------
// grid 512 (32 b x 16 4-row tiles), 256 threads (4 waves), wave = 1 output
// row x full 128 co (mi=8). Weights staged to LDS, 6-deep rotation, ONE
// vmcnt(0)+s_barrier per 3-tap phase (12 phases); W-issue post-barrier.
// xs SINGLE-buffered (LDS 74.5 KB -> 2 blocks/CU); per-cic xs reload pays
// one counted wait (VMWAIT(6): skips the 6 newer W loads) + extra barrier.
__global__ __launch_bounds__(256, 2) void conv_kernel(
    const unsigned short* __restrict__ xbfT,
    const unsigned short* __restrict__ dynw,
    const float* __restrict__ dynb,
    float* __restrict__ out)
{
    __shared__ __align__(16) unsigned short xs[6*66*32];      // 25344 B
    __shared__ __align__(16) unsigned short wsm[6][4096];     // 49152 B

    const int tid  = threadIdx.x;
    const int wave = tid >> 6;       // output row within tile (0..3)
    const int lane = tid & 63;
    const int l15  = lane & 15;
    const int g    = lane >> 4;

    // bijective XCD swizzle (512 blocks, 8 XCDs -> 64 contiguous per XCD)
    int bidx = ((blockIdx.x & 7) << 6) | (blockIdx.x >> 3);
    const int b  = bidx >> 4;
    const int r0 = (bidx & 15) << 2;

    f32x4 acc[8][4];
#pragma unroll
    for (int mi = 0; mi < 8; ++mi)
#pragma unroll
        for (int ni = 0; ni < 4; ++ni) acc[mi][ni] = (f32x4){0.f,0.f,0.f,0.f};

    const unsigned short* xsrcb = xbfT + (unsigned long long)b*(4ull*66*66*32);
    const unsigned short* wsrcb = dynw + (unsigned long long)b*(4ull*9*4096);

    // prologue: W(0..2) -> wsm[0..2], xs <- cic 0; full drain once
#pragma unroll
    for (int k = 0; k < 3; ++k) {
        const unsigned short* wsrc = wsrcb + (unsigned)(k*4096);
        gl2lds16(wsrc + (unsigned)tid*8,       wsm[k] + (unsigned)tid*8);
        gl2lds16(wsrc + (unsigned)(tid+256)*8, wsm[k] + (unsigned)(tid+256)*8);
    }
    {
        const unsigned short* src = xsrcb + (unsigned)r0*(66*32);
        for (int c = tid; c < 1584; c += 256) gl2lds16(src + c*8, xs + c*8);
    }
    __syncthreads();

#pragma unroll
    for (int p = 0; p < 12; ++p) {
        const int cic = p / 3;
        if (p > 0) {
            // bar A: everything issued >= 1 phase ago has landed -> cheap drain
            VMWAIT(0);
            __builtin_amdgcn_s_barrier();
            __builtin_amdgcn_sched_barrier(0);
        }
        // xs reload at cic boundary (post-barrier: all readers of the old
        // chunk finished before bar A). Issue BEFORE W so W counts as newer.
        const bool xreload = (p % 3) == 0 && p > 0;
        if (xreload) {
            const unsigned short* src = xsrcb + (unsigned)(cic*(66*66*32))
                                      + (unsigned)r0*(66*32);
            for (int c = tid; c < 1584; c += 256) gl2lds16(src + c*8, xs + c*8);
        }
        // issue next phase's 3 weight tiles (post-barrier: rotation-safe).
        // reads this phase touch wsm[(3p..3p+2)%6]; writes wsm[(3p+3..3p+5)%6].
        if (p < 11) {
#pragma unroll
            for (int k = 0; k < 3; ++k) {
                const int s = 3*p + 3 + k;
                const unsigned short* wsrc = wsrcb + (unsigned)(s*4096);
                unsigned short* wd = wsm[s % 6];
                gl2lds16(wsrc + (unsigned)tid*8,       wd + (unsigned)tid*8);
                gl2lds16(wsrc + (unsigned)(tid+256)*8, wd + (unsigned)(tid+256)*8);
            }
        }
        if (xreload) {
            // wait for xs only (skip the 6 newer W loads), then resync
            if (p < 11) { VMWAIT(6); } else { VMWAIT(0); }
            __builtin_amdgcn_s_barrier();
            __builtin_amdgcn_sched_barrier(0);
        }
        // compute 3 taps (ky = p%3, kx = 0..2) with no intervening sync
        const int ky   = p % 3;
        const int lrow = wave + ky;
        __builtin_amdgcn_s_setprio(1);
#pragma unroll
        for (int kx = 0; kx < 3; ++kx) {
            const unsigned short* wb = wsm[(3*p + kx) % 6];
            bf16x8 afrag[8];
#pragma unroll
            for (int mi = 0; mi < 8; ++mi)
                afrag[mi] = *(const bf16x8*)(wb + (unsigned)((mi*64 + lane)*8));
#pragma unroll
            for (int ni = 0; ni < 4; ++ni) {
                int lcol = 16*ni + l15 + kx;
                int boff = (lrow*66 + lcol)*64 + (((g + (lcol >> 1)) & 3) << 4);
                bf16x8 bfrag = *(const bf16x8*)((const char*)xs + boff);
#pragma unroll
                for (int mi = 0; mi < 8; ++mi)
                    acc[mi][ni] = __builtin_amdgcn_mfma_f32_16x16x32_bf16(
                                      afrag[mi], bfrag, acc[mi][ni], 0, 0, 0);
            }
        }
        __builtin_amdgcn_s_setprio(0);
    }

    // epilogue: co = 16*mi + g*4 + r ; y = r0 + wave ; x = 16*ni + l15
    const int y = r0 + wave;
#pragma unroll
    for (int mi = 0; mi < 8; ++mi) {
#pragma unroll
        for (int r = 0; r < 4; ++r) {
            int co = 16*mi + g*4 + r;
            float bias = dynb[b*128 + co];
            float* op = out + (((unsigned long long)(b*128 + co))*64 + y)*64;
#pragma unroll
            for (int ni = 0; ni < 4; ++ni)
                op[16*ni + l15] = acc[mi][ni][r] + bias;
        }
    }
}

extern "C" void kernel_launch(void* const* d_in, const int* in_sizes, int n_in,
                              void* d_out, int out_size, void* d_ws, size_t ws_size,
                              hipStream_t stream)
{
    const float* x     = (const float*)d_in[0];
    const float* stats = (const float*)d_in[1];
    const float* W1    = (const float*)d_in[2];
    const float* b1    = (const float*)d_in[3];
    const float* W2    = (const float*)d_in[4];
    const float* b2    = (const float*)d_in[5];
    const float* wexp  = (const float*)d_in[6];
    const float* bexp  = (const float*)d_in[7];
    float* out = (float*)d_out;

    char* ws = (char*)d_ws;
    float* dynb           = (float*)(ws + 512);                      // 16 KB
    unsigned short* dynw  = (unsigned short*)(ws + 32768);           // 9,437,184 B
    unsigned short* xbfT  = (unsigned short*)(ws + 32768 + 9437184); // 35,684,352 B

    prep_kernel<<<2624, 256, 0, stream>>>(x, xbfT, stats, W1, b1, W2, b2,
                                          wexp, bexp, dynw, dynb);
    conv_kernel<<<512, 256, 0, stream>>>(xbfT, dynw, dynb, out);
}

// Round 11
// 59.582 us; speedup vs baseline: 1.6900x; 1.1021x over previous
//
#include <hip/hip_runtime.h>
#include <hip/hip_bf16.h>

// StatDynamicConv2d: routing MLP -> expert-mixed 3x3 conv (per-sample weights)
// B=32, Cin=Cout=128, H=W=64, E=4, K=3, pad=1, stride=1.
//
// ws layout:
//   [512, 512+16384)       dynb[32][128] f32
//   [32768, +9437184)      dynw[32][4cic][9tap][8mi][64lane][8] bf16
//                          (MFMA A-fragment order)
// xbfT intermediate is GONE: conv reads x (f32) directly and transposes
// in-register (8x8 u16 across 8 lanes) into the swizzled xs LDS layout.

typedef short bf16x8 __attribute__((ext_vector_type(8)));
typedef float f32x4  __attribute__((ext_vector_type(4)));

#define VMWAIT(n) asm volatile("s_waitcnt vmcnt(" #n ")" ::: "memory")

static __device__ __forceinline__ unsigned short f2bf(float f) {
    unsigned u = __float_as_uint(f);
    u = u + 0x7FFFu + ((u >> 16) & 1u);   // round-to-nearest-even
    return (unsigned short)(u >> 16);
}

static __device__ __forceinline__ void gl2lds16(const unsigned short* g, unsigned short* l) {
    __builtin_amdgcn_global_load_lds(
        (const __attribute__((address_space(1))) unsigned int*)g,
        (__attribute__((address_space(3))) unsigned int*)l,
        16, 0, 0);
}

// ---------------- kernel P: dynamic weights (router inlined) ----------------
// grid 512 (= 128 co x 4 bgroups), 256 threads
__global__ void prep_kernel(const float* __restrict__ stats, const float* __restrict__ W1,
                            const float* __restrict__ b1, const float* __restrict__ W2,
                            const float* __restrict__ b2, const float* __restrict__ wexp,
                            const float* __restrict__ bexp, unsigned short* __restrict__ dynw,
                            float* __restrict__ dynb)
{
    __shared__ float ls[4*1152];
    __shared__ float lr[32*4];
    const int tid = threadIdx.x;
    const int co  = blockIdx.x & 127;
    const int bg  = blockIdx.x >> 7;

    if (tid < 32) {                   // recompute tiny router MLP per block (cheap)
        float s[6];
#pragma unroll
        for (int i = 0; i < 6; ++i) s[i] = stats[tid*6 + i];
        float h[16];
#pragma unroll
        for (int j = 0; j < 16; ++j) {
            float a = b1[j];
#pragma unroll
            for (int i = 0; i < 6; ++i) a += W1[j*6+i]*s[i];
            h[j] = a > 0.f ? a : 0.f;
        }
        float lg[4];
#pragma unroll
        for (int e = 0; e < 4; ++e) {
            float a = b2[e];
#pragma unroll
            for (int j = 0; j < 16; ++j) a += W2[e*16+j]*h[j];
            lg[e] = a;
        }
        float m = fmaxf(fmaxf(lg[0],lg[1]), fmaxf(lg[2],lg[3]));
        float ex[4], sum = 0.f;
#pragma unroll
        for (int e = 0; e < 4; ++e) { ex[e] = expf(lg[e]-m); sum += ex[e]; }
        float inv = 1.f / sum;
#pragma unroll
        for (int e = 0; e < 4; ++e) lr[tid*4+e] = ex[e]*inv;
    }
    for (int i = tid; i < 4*1152; i += 256) {
        int e = i / 1152, j = i - e*1152;
        ls[i] = wexp[((unsigned long long)(e*128 + co))*1152 + j];
    }
    __syncthreads();

    if (bg == 0 && tid < 32) {
        float sb = 0.f;
#pragma unroll
        for (int e = 0; e < 4; ++e) sb += lr[tid*4+e] * bexp[e*128 + co];
        dynb[tid*128 + co] = sb;
    }

    const int ci  = tid & 127;
    const int tp0 = tid >> 7;
    const int cic = ci >> 5;
    const int g   = (ci >> 3) & 3;
    const int jj  = ci & 7;
    const int mi  = co >> 4;
    const int l15 = co & 15;
    for (int bb = bg*8; bb < bg*8 + 8; ++bb) {
        float r0 = lr[bb*4+0], r1 = lr[bb*4+1], r2 = lr[bb*4+2], r3 = lr[bb*4+3];
#pragma unroll
        for (int pp = 0; pp < 5; ++pp) {
            int tap = 2*pp + tp0;
            if (tap < 9) {
                int j = ci*9 + tap;
                float v = r0*ls[j] + r1*ls[1152+j] + r2*ls[2*1152+j] + r3*ls[3*1152+j];
                dynw[((((unsigned long long)(bb*4 + cic)*9 + tap)*8 + mi)*64 + g*16 + l15)*8 + jj] = f2bf(v);
            }
        }
    }
}

// ---------------- kernel D: implicit-GEMM conv, bf16 MFMA ----------------
// grid 512 (32 b x 16 4-row tiles), 256 threads (4 waves), wave = 1 output
// row x full 128 co (mi=8). Weights staged to LDS (6-deep rotation, one
// vmcnt(0)+s_barrier per 3-tap phase). x staged DIRECTLY from f32 global:
// per-oct 8x8 u16 in-register transpose -> swizzled xs writes.
__global__ __launch_bounds__(256, 2) void conv_kernel(
    const float* __restrict__ x,
    const unsigned short* __restrict__ dynw,
    const float* __restrict__ dynb,
    float* __restrict__ out)
{
    __shared__ __align__(16) unsigned short xs[6*66*32];      // 25344 B
    __shared__ __align__(16) unsigned short wsm[6][4096];     // 49152 B

    const int tid  = threadIdx.x;
    const int wave = tid >> 6;       // output row within tile (0..3)
    const int lane = tid & 63;
    const int l15  = lane & 15;
    const int g    = lane >> 4;
    // staging ids: oct = 8 consecutive threads
    const int so    = tid & 7;       // ci-within-8 (pre-transpose row)
    const int scg   = (tid >> 3) & 3;    // 8-ci chunk index (0..3)
    const int scolO = (tid >> 5) & 7;    // 8-col group (0..7)

    // bijective XCD swizzle (512 blocks, 8 XCDs -> 64 contiguous per XCD)
    int bidx = ((blockIdx.x & 7) << 6) | (blockIdx.x >> 3);
    const int b  = bidx >> 4;
    const int r0 = (bidx & 15) << 2;

    f32x4 acc[8][4];
#pragma unroll
    for (int mi = 0; mi < 8; ++mi)
#pragma unroll
        for (int ni = 0; ni < 4; ++ni) acc[mi][ni] = (f32x4){0.f,0.f,0.f,0.f};

    const float* xsrcb = x + (unsigned long long)b*(128ull*64*64);
    const unsigned short* wsrcb = dynw + (unsigned long long)b*(4ull*9*4096);

    // x-staging: per unit kk (row kk of 6): lane (so) loads 8 cols x 1 ci as
    // 2 float4, converts to 4 u32 (2 bf16 each), 2-stage butterfly transpose,
    // writes 2x ds_write_b64 (two cols, own 4-ci half).
#define XISSUE(kk)                                                             \
    do {                                                                       \
        int grow_ = r0 + (kk) - 1;                                             \
        int growc_ = grow_ < 0 ? 0 : (grow_ > 63 ? 63 : grow_);                \
        const float* xp_ = xsrcb + (((unsigned long long)(cic_*32 + scg*8 + so))*64 \
                            + growc_)*64 + scolO*8;                            \
        xv[(kk)%3][0] = *(const float4*)xp_;                                   \
        xv[(kk)%3][1] = *(const float4*)(xp_ + 4);                             \
    } while (0)

#define XPROC(kk)                                                              \
    do {                                                                       \
        int grow_ = r0 + (kk) - 1;                                             \
        bool oob_ = (grow_ < 0) || (grow_ > 63);                               \
        float4 v0 = xv[(kk)%3][0], v1 = xv[(kk)%3][1];                         \
        unsigned ra = oob_ ? 0u : (f2bf(v0.x) | ((unsigned)f2bf(v0.y) << 16)); \
        unsigned rb = oob_ ? 0u : (f2bf(v0.z) | ((unsigned)f2bf(v0.w) << 16)); \
        unsigned rc = oob_ ? 0u : (f2bf(v1.x) | ((unsigned)f2bf(v1.y) << 16)); \
        unsigned rd = oob_ ? 0u : (f2bf(v1.z) | ((unsigned)f2bf(v1.w) << 16)); \
        unsigned pa = __shfl_xor(ra,1), pb = __shfl_xor(rb,1);                 \
        unsigned pc = __shfl_xor(rc,1), pd = __shfl_xor(rd,1);                 \
        bool oddl = so & 1;                                                    \
        unsigned sa = oddl ? ((pa>>16)|(ra&0xFFFF0000u)) : ((ra&0xFFFFu)|(pa<<16)); \
        unsigned sb = oddl ? ((pb>>16)|(rb&0xFFFF0000u)) : ((rb&0xFFFFu)|(pb<<16)); \
        unsigned sc = oddl ? ((pc>>16)|(rc&0xFFFF0000u)) : ((rc&0xFFFFu)|(pc<<16)); \
        unsigned sd = oddl ? ((pd>>16)|(rd&0xFFFF0000u)) : ((rd&0xFFFFu)|(pd<<16)); \
        unsigned qa = __shfl_xor(sa,2), qb = __shfl_xor(sb,2);                 \
        unsigned qc = __shfl_xor(sc,2), qd = __shfl_xor(sd,2);                 \
        bool hi2 = so & 2;                                                     \
        unsigned A0 = hi2 ? qc : sa, A1 = hi2 ? sc : qa;                       \
        unsigned B0 = hi2 ? qd : sb, B1 = hi2 ? sd : qb;                       \
        int cA_ = (so & 1) + (hi2 ? 4 : 0);                                    \
        int half8_ = (so >> 2) << 3;                                           \
        int lcolA_ = scolO*8 + cA_ + 1;                                        \
        int lcolB_ = lcolA_ + 2;                                               \
        int byteA_ = ((kk)*66 + lcolA_)*64 + (((scg + (lcolA_>>1)) & 3)<<4) + half8_; \
        int byteB_ = ((kk)*66 + lcolB_)*64 + (((scg + (lcolB_>>1)) & 3)<<4) + half8_; \
        *(uint2*)((char*)xs + byteA_) = make_uint2(A0, A1);                    \
        *(uint2*)((char*)xs + byteB_) = make_uint2(B0, B1);                    \
    } while (0)

    // full stage: issue u0,u1; issue 3 W tiles (6 gl2lds, stay in flight);
    // ladder: wait oldest unit, process, issue unit+2. Never drains W unless DRAIN.
#define XSTAGE(CIC_, WFIRST_, DRAIN_)                                          \
    do {                                                                       \
        const int cic_ = (CIC_);                                               \
        float4 xv[3][2];                                                       \
        XISSUE(0); XISSUE(1);                                                  \
        _Pragma("unroll")                                                      \
        for (int t = 0; t < 3; ++t) {                                          \
            const unsigned short* wsrc_ = wsrcb + (unsigned)(((WFIRST_) + t)*4096); \
            unsigned short* wd_ = wsm[((WFIRST_) + t) % 6];                    \
            gl2lds16(wsrc_ + (unsigned)tid*8,       wd_ + (unsigned)tid*8);    \
            gl2lds16(wsrc_ + (unsigned)(tid+256)*8, wd_ + (unsigned)(tid+256)*8); \
        }                                                                      \
        VMWAIT(8); XPROC(0); XISSUE(2);                                        \
        VMWAIT(8); XPROC(1); XISSUE(3);                                        \
        VMWAIT(8); XPROC(2); XISSUE(4);                                        \
        VMWAIT(8); XPROC(3); XISSUE(5);                                        \
        VMWAIT(8); XPROC(4);                                                   \
        if (DRAIN_) { VMWAIT(0); } else { VMWAIT(6); }                         \
        XPROC(5);                                                              \
    } while (0)

    // prologue: zero halo cols (lcol 0,65 — never rewritten), stage cic0 + W(0..2)
    if (tid < 48) {
        int zrow = tid >> 3, zcol = ((tid >> 2) & 1) ? 65 : 0, zch = tid & 3;
        *(uint4*)((char*)xs + (zrow*66 + zcol)*64 + zch*16) = make_uint4(0,0,0,0);
    }
    XSTAGE(0, 0, true);
    asm volatile("s_waitcnt lgkmcnt(0)" ::: "memory");
    __syncthreads();

#pragma unroll
    for (int p = 0; p < 12; ++p) {
        const int cic = p / 3;
        if (p > 0) {
            // bar A: W(p) (issued a full phase ago) landed; cheap drain
            VMWAIT(0);
            __builtin_amdgcn_s_barrier();
            __builtin_amdgcn_sched_barrier(0);
        }
        if ((p % 3) == 0 && p > 0) {
            // cic boundary: restage xs from x (post-bar: old readers done),
            // issue W(p+1) inside; then make writes visible before compute.
            XSTAGE(cic, 3*p + 3, false);
            asm volatile("s_waitcnt lgkmcnt(0)" ::: "memory");
            __builtin_amdgcn_s_barrier();
            __builtin_amdgcn_sched_barrier(0);
        } else if (p < 11) {
            // issue next phase's 3 weight tiles (reads touch {3p..3p+2}%6,
            // writes {3p+3..3p+5}%6 — disjoint)
#pragma unroll
            for (int t = 0; t < 3; ++t) {
                const int s = 3*p + 3 + t;
                const unsigned short* wsrc = wsrcb + (unsigned)(s*4096);
                unsigned short* wd = wsm[s % 6];
                gl2lds16(wsrc + (unsigned)tid*8,       wd + (unsigned)tid*8);
                gl2lds16(wsrc + (unsigned)(tid+256)*8, wd + (unsigned)(tid+256)*8);
            }
        }
        // compute 3 taps (ky = p%3, kx = 0..2), no intervening sync
        const int ky   = p % 3;
        const int lrow = wave + ky;
        __builtin_amdgcn_s_setprio(1);
#pragma unroll
        for (int kx = 0; kx < 3; ++kx) {
            const unsigned short* wb = wsm[(3*p + kx) % 6];
            bf16x8 afrag[8];
#pragma unroll
            for (int mi = 0; mi < 8; ++mi)
                afrag[mi] = *(const bf16x8*)(wb + (unsigned)((mi*64 + lane)*8));
#pragma unroll
            for (int ni = 0; ni < 4; ++ni) {
                int lcol = 16*ni + l15 + kx;
                int boff = (lrow*66 + lcol)*64 + (((g + (lcol >> 1)) & 3) << 4);
                bf16x8 bfrag = *(const bf16x8*)((const char*)xs + boff);
#pragma unroll
                for (int mi = 0; mi < 8; ++mi)
                    acc[mi][ni] = __builtin_amdgcn_mfma_f32_16x16x32_bf16(
                                      afrag[mi], bfrag, acc[mi][ni], 0, 0, 0);
            }
        }
        __builtin_amdgcn_s_setprio(0);
    }

    // epilogue: co = 16*mi + g*4 + r ; y = r0 + wave ; x = 16*ni + l15
    const int y = r0 + wave;
#pragma unroll
    for (int mi = 0; mi < 8; ++mi) {
#pragma unroll
        for (int r = 0; r < 4; ++r) {
            int co = 16*mi + g*4 + r;
            float bias = dynb[b*128 + co];
            float* op = out + (((unsigned long long)(b*128 + co))*64 + y)*64;
#pragma unroll
            for (int ni = 0; ni < 4; ++ni)
                op[16*ni + l15] = acc[mi][ni][r] + bias;
        }
    }
#undef XSTAGE
#undef XPROC
#undef XISSUE
}

extern "C" void kernel_launch(void* const* d_in, const int* in_sizes, int n_in,
                              void* d_out, int out_size, void* d_ws, size_t ws_size,
                              hipStream_t stream)
{
    const float* x     = (const float*)d_in[0];
    const float* stats = (const float*)d_in[1];
    const float* W1    = (const float*)d_in[2];
    const float* b1    = (const float*)d_in[3];
    const float* W2    = (const float*)d_in[4];
    const float* b2    = (const float*)d_in[5];
    const float* wexp  = (const float*)d_in[6];
    const float* bexp  = (const float*)d_in[7];
    float* out = (float*)d_out;

    char* ws = (char*)d_ws;
    float* dynb           = (float*)(ws + 512);                      // 16 KB
    unsigned short* dynw  = (unsigned short*)(ws + 32768);           // 9,437,184 B

    prep_kernel<<<512, 256, 0, stream>>>(stats, W1, b1, W2, b2, wexp, bexp, dynw, dynb);
    conv_kernel<<<512, 256, 0, stream>>>(x, dynw, dynb, out);
}